// Round 8
// baseline (741.356 us; speedup 1.0000x reference)
//
#include <hip/hip_runtime.h>
#include <stdint.h>

// MixtureOfSoftmaxes: B=1024, H=4, D=256, V=100000
// out[b,v] = sum_h pi[b,h] * softmax_v(proj[b,h,:]·emb[v,:])
// No-max softmax (|logits| < ~3), base-2 (embB pre-scaled by log2e):
//   pass C: part[vb*2+wc][m] = sum_{v} exp2(l'); reduce -> w = pi/s
//   pass D: out[b,v] = sum_h w[m]*exp2(l')
// R8: B (emb) register-resident for full K=256 (128 VGPR/wave), A streams via
// 2x16KB LDS dbuf -> 2 blocks/CU (cross-block overlap hides barriers). 16
// pipelined k-steps/block (8 m-tiles x BK=128), counted vmcnt ledger, XCD swizzle.

#define VOCAB 100000
#define NVB 782       // v-blocks of 128
#define NSTRIPS 1564  // NVB * 2 v-wave halves
#define VPAD 100096

typedef __attribute__((ext_vector_type(8))) short short8;
typedef __attribute__((ext_vector_type(4))) float f32x4;

__device__ __forceinline__ short f2bf(float f) {
  uint32_t u = __float_as_uint(f);
  u = (u + 0x7FFFu + ((u >> 16) & 1u)) >> 16;
  return (short)u;
}

#define VMCNT(n) asm volatile("s_waitcnt vmcnt(" #n ")" ::: "memory")
#define LGKM0()  asm volatile("s_waitcnt lgkmcnt(0)" ::: "memory")
#define SCHED0() __builtin_amdgcn_sched_barrier(0)
#define BAR()    __builtin_amdgcn_s_barrier()

// ---------------- kernel 1: proj = tanh(x @ proj_mat^T) -> bf16 [4096 x 256] ----
__global__ __launch_bounds__(256) void proj_kernel(const float* __restrict__ x,
                                                   const float* __restrict__ pm,
                                                   short* __restrict__ projA) {
  __shared__ float xs[64][36];
  __shared__ float ps[64][36];
  const int tid = threadIdx.x;
  const int tx = tid & 15, ty = tid >> 4;
  const int m0 = blockIdx.y * 64, n0 = blockIdx.x * 64;
  float acc[4][4];
#pragma unroll
  for (int i = 0; i < 4; i++)
#pragma unroll
    for (int j = 0; j < 4; j++) acc[i][j] = 0.f;

  for (int k0 = 0; k0 < 256; k0 += 32) {
    const int r = tid >> 2, c = (tid & 3) * 8;
    *(float4*)&xs[r][c]     = *(const float4*)&x[(m0 + r) * 256 + k0 + c];
    *(float4*)&xs[r][c + 4] = *(const float4*)&x[(m0 + r) * 256 + k0 + c + 4];
    *(float4*)&ps[r][c]     = *(const float4*)&pm[(n0 + r) * 256 + k0 + c];
    *(float4*)&ps[r][c + 4] = *(const float4*)&pm[(n0 + r) * 256 + k0 + c + 4];
    __syncthreads();
#pragma unroll
    for (int kk = 0; kk < 32; kk += 4) {
      float4 xa[4], pb[4];
#pragma unroll
      for (int i = 0; i < 4; i++) xa[i] = *(const float4*)&xs[ty * 4 + i][kk];
#pragma unroll
      for (int j = 0; j < 4; j++) pb[j] = *(const float4*)&ps[tx * 4 + j][kk];
#pragma unroll
      for (int i = 0; i < 4; i++)
#pragma unroll
        for (int j = 0; j < 4; j++)
          acc[i][j] += xa[i].x * pb[j].x + xa[i].y * pb[j].y +
                       xa[i].z * pb[j].z + xa[i].w * pb[j].w;
    }
    __syncthreads();
  }
#pragma unroll
  for (int i = 0; i < 4; i++)
#pragma unroll
    for (int j = 0; j < 4; j++)
      projA[(size_t)(m0 + ty * 4 + i) * 1024 + (n0 + tx * 4 + j)] = f2bf(tanhf(acc[i][j]));
}

// ---------------- kernel 2: pi = softmax(x @ mix_mat^T)  [1024 x 4] --------------
__global__ __launch_bounds__(256) void pi_kernel(const float* __restrict__ x,
                                                 const float* __restrict__ mm,
                                                 float* __restrict__ pi) {
  int b = blockIdx.x * 256 + threadIdx.x;
  if (b >= 1024) return;
  float acc[4] = {0.f, 0.f, 0.f, 0.f};
  for (int k = 0; k < 256; k += 4) {
    float4 xv = *(const float4*)&x[(size_t)b * 256 + k];
#pragma unroll
    for (int h = 0; h < 4; h++) {
      float4 mv = *(const float4*)&mm[h * 256 + k];
      acc[h] += xv.x * mv.x + xv.y * mv.y + xv.z * mv.z + xv.w * mv.w;
    }
  }
  float mx = fmaxf(fmaxf(acc[0], acc[1]), fmaxf(acc[2], acc[3]));
  float e[4], ssum = 0.f;
#pragma unroll
  for (int h = 0; h < 4; h++) { e[h] = __expf(acc[h] - mx); ssum += e[h]; }
#pragma unroll
  for (int h = 0; h < 4; h++) pi[b * 4 + h] = e[h] / ssum;
}

// ------- kernel 3: embB = bf16(emb * log2e), zero-padded to VPAD rows -----------
__global__ __launch_bounds__(256) void embB_kernel(const float* __restrict__ emb,
                                                   short* __restrict__ embB) {
  size_t i = ((size_t)blockIdx.x * 256 + threadIdx.x) * 8;  // element index
  size_t row = i >> 8;
  const float C = 1.44269504088896f;  // log2(e): exp(l) == exp2(l*C)
  short8 b8;
  if (row < VOCAB) {
    float4 f0 = *(const float4*)&emb[i];
    float4 f1 = *(const float4*)&emb[i + 4];
    b8[0] = f2bf(f0.x * C); b8[1] = f2bf(f0.y * C); b8[2] = f2bf(f0.z * C); b8[3] = f2bf(f0.w * C);
    b8[4] = f2bf(f1.x * C); b8[5] = f2bf(f1.y * C); b8[6] = f2bf(f1.z * C); b8[7] = f2bf(f1.w * C);
  } else {
#pragma unroll
    for (int j = 0; j < 8; ++j) b8[j] = 0;
  }
  *(short8*)&embB[i] = b8;
}

// ---------------- big GEMM ------------------------------------------------------
// Block: 256 thr (4 waves: wr=m-half(32), wc=v-half(64)); v-block 128 cols,
// m-range 512 rows = 8 m-tiles of 64. Wave tile 32m x 64v, acc[2][4].
// B (embB) in regs: Bf[ni=4][ks=8]. A: LDS dbuf 2 x (64 rows x 256B) = 32 KB,
// chunk-xor swizzle c^(r&7) (pre-swizzled source, linear LDS dest).
// k-step g (0..15): mt=g>>1, KH=g&1 (K-half of 128). Stage(g+1) at top of g.
// Ledger: stage=4 loads; epilogue stores S (MODE0: 2x float4=2, MODE1: 8).
// Checkpoints: even g: VMCNT(4+S); odd g: VMCNT(4); g=15: VMCNT(0).

template <int VM, bool DO_STAGE, int KH>
__device__ __forceinline__ void k_step(char* sm, const char* gA0, int sOff, int wid,
                                       const int (&aadr)[4], const short8 (&Bf)[4][8],
                                       f32x4 (&acc)[2][4]) {
  constexpr int buf = KH;  // even g -> buf0, odd -> buf1
  if constexpr (DO_STAGE) {
#pragma unroll
    for (int j = 0; j < 4; ++j)
      __builtin_amdgcn_global_load_lds(
          (const __attribute__((address_space(1))) void*)(gA0 + sOff + j * 8192),
          (__attribute__((address_space(3))) void*)(sm + (buf ^ 1) * 16384 + j * 4096 + wid * 1024),
          16, 0, 0);
  }
  SCHED0();
  if constexpr (VM == 12)      { VMCNT(12); }
  else if constexpr (VM == 6)  { VMCNT(6); }
  else if constexpr (VM == 4)  { VMCNT(4); }
  else                         { VMCNT(0); }
  BAR();  // buffer `buf` staged for all waves
  short8 a[2][4];
#pragma unroll
  for (int mi = 0; mi < 2; ++mi)
#pragma unroll
    for (int ks = 0; ks < 2; ++ks)
      a[mi][ks] = *(const short8*)(sm + buf * 16384 + mi * 4096 + aadr[ks]);
  __builtin_amdgcn_s_setprio(1);
#pragma unroll
  for (int ks = 0; ks < 2; ++ks)
#pragma unroll
    for (int mi = 0; mi < 2; ++mi)
#pragma unroll
      for (int ni = 0; ni < 4; ++ni)
        acc[mi][ni] = __builtin_amdgcn_mfma_f32_16x16x32_bf16(a[mi][ks], Bf[ni][KH * 4 + ks],
                                                              acc[mi][ni], 0, 0, 0);
  __builtin_amdgcn_s_setprio(0);
#pragma unroll
  for (int mi = 0; mi < 2; ++mi)
#pragma unroll
    for (int ks = 2; ks < 4; ++ks)
      a[mi][ks] = *(const short8*)(sm + buf * 16384 + mi * 4096 + aadr[ks]);
  LGKM0();   // our reads of `buf` done
  SCHED0();
  BAR();     // all waves done reading `buf` -> next k-step may restage it
  __builtin_amdgcn_s_setprio(1);  // pure-register cluster overlaps next stage/reads
#pragma unroll
  for (int ks = 2; ks < 4; ++ks)
#pragma unroll
    for (int mi = 0; mi < 2; ++mi)
#pragma unroll
      for (int ni = 0; ni < 4; ++ni)
        acc[mi][ni] = __builtin_amdgcn_mfma_f32_16x16x32_bf16(a[mi][ks], Bf[ni][KH * 4 + ks],
                                                              acc[mi][ni], 0, 0, 0);
  __builtin_amdgcn_s_setprio(0);
}

template <int MODE>
__device__ __forceinline__ void epilogue(int mt, int m0, int v0, int vb, int wr, int wc,
                                         int l15, int l4, int tid, int bid,
                                         const float* __restrict__ w, float* __restrict__ part,
                                         float* __restrict__ dump, float* __restrict__ out,
                                         f32x4 (&acc)[2][4]) {
  if (MODE == 0) {
#pragma unroll
    for (int mi = 0; mi < 2; ++mi) {
      float p[4] = {0.f, 0.f, 0.f, 0.f};
#pragma unroll
      for (int ni = 0; ni < 4; ++ni) {
        int v = v0 + wc * 64 + ni * 16 + l15;
        bool ok = v < VOCAB;
#pragma unroll
        for (int r = 0; r < 4; ++r) {
          float e = exp2f(acc[mi][ni][r]);
          p[r] += ok ? e : 0.f;
        }
      }
#pragma unroll
      for (int r = 0; r < 4; ++r) {
        p[r] += __shfl_xor(p[r], 1, 64);
        p[r] += __shfl_xor(p[r], 2, 64);
        p[r] += __shfl_xor(p[r], 4, 64);
        p[r] += __shfl_xor(p[r], 8, 64);
      }
      // l15==0 has 4 active lanes per wave -> instruction always issues (uniform count)
      if (l15 == 0) {
        int m = m0 + mt * 64 + wr * 32 + mi * 16 + l4 * 4;
        float4 pv = {p[0], p[1], p[2], p[3]};
        *(float4*)(part + (size_t)(vb * 2 + wc) * 4096 + m) = pv;
      }
    }
  } else {
#pragma unroll
    for (int mi = 0; mi < 2; ++mi) {
      int mbase = m0 + mt * 64 + wr * 32 + mi * 16;
      float4 wv = *(const float4*)&w[mbase + l4 * 4];
      size_t brow = (size_t)(mbase >> 2) + l4;
#pragma unroll
      for (int ni = 0; ni < 4; ++ni) {
        int v = v0 + wc * 64 + ni * 16 + l15;
        float val = wv.x * exp2f(acc[mi][ni][0]) + wv.y * exp2f(acc[mi][ni][1]) +
                    wv.z * exp2f(acc[mi][ni][2]) + wv.w * exp2f(acc[mi][ni][3]);
        // unconditional issue (dump redirect) -> uniform vmcnt counts even at vocab tail
        float* tgt = (v < VOCAB) ? (out + brow * VOCAB + v)
                                 : (dump + ((bid & 255) * 256 + tid));
        *tgt = val;
      }
    }
  }
#pragma unroll
  for (int mi = 0; mi < 2; ++mi)
#pragma unroll
    for (int ni = 0; ni < 4; ++ni) acc[mi][ni] = (f32x4){0.f, 0.f, 0.f, 0.f};
}

template <int MODE>
__global__ __launch_bounds__(256, 2) void mos_gemm(const short* __restrict__ projA_s,
                                                   const short* __restrict__ embB_s,
                                                   const float* __restrict__ w,
                                                   float* __restrict__ part,
                                                   float* __restrict__ dump,
                                                   float* __restrict__ out) {
  __shared__ __align__(16) char sm[32768];
  const int tid = threadIdx.x;
  const int lane = tid & 63, wid = tid >> 6;
  const int wr = wid >> 1, wc = wid & 1;
  const int l15 = lane & 15, l4 = lane >> 4;
  const int bid = blockIdx.x;

  // bijective XCD swizzle: 6256 = 8*782; consecutive sw share vb -> embB L2-local
  const int sw = (bid & 7) * 782 + (bid >> 3);
  const int vb = sw >> 3, me = sw & 7;
  const int v0 = vb * 128, m0 = me * 512;

  // A staging source (pre-swizzled): thread -> (row r = tid>>4 (+16 per j), chunk c = tid&15)
  const char* gA0 = (const char*)projA_s + (size_t)(m0 + (tid >> 4)) * 512 +
                    (((tid & 15) ^ ((tid >> 4) & 7)) << 4);
  // per-lane ds-read addresses (A frag (mi,ks): row wr*32+mi*16+l15, chunk ks*4+l4)
  int aadr[4];
#pragma unroll
  for (int ks = 0; ks < 4; ++ks)
    aadr[ks] = wr * 8192 + l15 * 256 + ((((ks * 4) + l4) ^ (l15 & 7)) << 4);

  // ---- prologue: stage g=0 FIRST (oldest in vmcnt ledger), then B-reg loads ----
#pragma unroll
  for (int j = 0; j < 4; ++j)
    __builtin_amdgcn_global_load_lds(
        (const __attribute__((address_space(1))) void*)(gA0 + j * 8192),
        (__attribute__((address_space(3))) void*)(sm + j * 4096 + wid * 1024), 16, 0, 0);
  SCHED0();

  short8 Bf[4][8];  // emb fragments, full K=256, register-resident (128 VGPR)
  {
    const char* bsrc = (const char*)embB_s + (size_t)(v0 + wc * 64 + l15) * 512 + l4 * 16;
#pragma unroll
    for (int ni = 0; ni < 4; ++ni)
#pragma unroll
      for (int ks = 0; ks < 8; ++ks)
        Bf[ni][ks] = *(const short8*)(bsrc + ni * 8192 + ks * 64);
  }
  SCHED0();

  f32x4 acc[2][4];
#pragma unroll
  for (int mi = 0; mi < 2; ++mi)
#pragma unroll
    for (int ni = 0; ni < 4; ++ni) acc[mi][ni] = (f32x4){0.f, 0.f, 0.f, 0.f};

  constexpr int VME = (MODE == 0) ? 6 : 12;  // 4 stage loads + S epilogue stores

#pragma unroll 1
  for (int mt = 0; mt < 7; ++mt) {
    k_step<VME, true, 0>(sm, gA0, mt * 32768 + 256, wid, aadr, Bf, acc);
    k_step<4, true, 1>(sm, gA0, (mt + 1) * 32768, wid, aadr, Bf, acc);
    epilogue<MODE>(mt, m0, v0, vb, wr, wc, l15, l4, tid, bid, w, part, dump, out, acc);
  }
  k_step<VME, true, 0>(sm, gA0, 7 * 32768 + 256, wid, aadr, Bf, acc);
  k_step<0, false, 1>(sm, gA0, 0, wid, aadr, Bf, acc);
  epilogue<MODE>(7, m0, v0, vb, wr, wc, l15, l4, tid, bid, w, part, dump, out, acc);
}

// ---------------- reduce partials + w = pi / s ----------------------------------
__global__ __launch_bounds__(256) void reduce_w(const float* __restrict__ part,
                                                const float* __restrict__ pi,
                                                float* __restrict__ w) {
  int m = blockIdx.x * 256 + threadIdx.x;  // 0..4095
  float sum = 0.f;
  for (int c = 0; c < NSTRIPS; ++c) sum += part[(size_t)c * 4096 + m];
  w[m] = pi[m] / sum;
}

extern "C" void kernel_launch(void* const* d_in, const int* in_sizes, int n_in,
                              void* d_out, int out_size, void* d_ws, size_t ws_size,
                              hipStream_t stream) {
  const float* x        = (const float*)d_in[0];
  const float* proj_mat = (const float*)d_in[1];
  const float* mix_mat  = (const float*)d_in[2];
  const float* emb      = (const float*)d_in[3];
  float* out = (float*)d_out;

  char* ws = (char*)d_ws;
  short* projA = (short*)ws;                           // bf16 [4096][256] = 2 MB
  float* pi    = (float*)(ws + (2u << 20));            // [4096]
  float* w     = (float*)(ws + (2u << 20) + 16384);    // [4096]
  short* embB  = (short*)(ws + (4u << 20));            // bf16 [100096][256] = 48.9 MB
  float* part  = (float*)(ws + (4u << 20) + (size_t)VPAD * 512);  // [1564][4096] = 25.6 MB
  float* dump  = part + (size_t)NSTRIPS * 4096;        // 256 KB junk sink

  dim3 g1(16, 16);
  proj_kernel<<<g1, 256, 0, stream>>>(x, proj_mat, projA);
  pi_kernel<<<4, 256, 0, stream>>>(x, mix_mat, pi);
  embB_kernel<<<VPAD / 8, 256, 0, stream>>>(emb, embB);

  mos_gemm<0><<<8 * NVB, 256, 0, stream>>>(projA, embB, nullptr, part, dump, nullptr);
  reduce_w<<<16, 256, 0, stream>>>(part, pi, w);
  mos_gemm<1><<<8 * NVB, 256, 0, stream>>>(projA, embB, w, nullptr, dump, out);
}

// Round 9
// 738.179 us; speedup vs baseline: 1.0043x; 1.0043x over previous
//
#include <hip/hip_runtime.h>
#include <stdint.h>

// MixtureOfSoftmaxes: B=1024, H=4, D=256, V=100000
// out[b,v] = sum_h pi[b,h] * softmax_v(proj[b,h,:]·emb[v,:])
// No-max softmax (|logits| < ~3), base-2 (embB pre-scaled by log2e):
//   pass C: part[vt][m] = sum_{v in vt} exp2(l'); reduce -> w = pi/s
//   pass D: out[b,v] = sum_h w[m]*exp2(l')
// R9: ZERO-LDS zero-barrier GEMM. projF stored in MFMA-fragment order so A-frag
// loads are coalesced 1KB dwordx4 from L2; emb fragments register-resident per
// 64-v wave tile (Bf 128 VGPR, loaded once, reused over 16 m-tiles). Waves fully
// independent: epilogue VALU of one wave hides under sibling's MFMA.

#define VOCAB 100000
#define NVT 1564   // v-tiles of 64 (covers 100096)
#define VPAD 100096

typedef __attribute__((ext_vector_type(8))) short short8;
typedef __attribute__((ext_vector_type(4))) float f32x4;

__device__ __forceinline__ short f2bf(float f) {
  uint32_t u = __float_as_uint(f);
  u = (u + 0x7FFFu + ((u >> 16) & 1u)) >> 16;
  return (short)u;
}

// ---------------- kernel 1: proj = tanh(x @ proj_mat^T) -> projF (frag order) ---
// frag layout: elem addr = ((((m>>6)*8 + (k>>5))*4 + ((m>>4)&3))*64
//                           + ((k>>3)&3)*16 + (m&15))*8 + (k&7)
// where m = b*4 + (c>>8)  (flat row of [4096][256] view), k = c&255.
__global__ __launch_bounds__(256) void proj_kernel(const float* __restrict__ x,
                                                   const float* __restrict__ pm,
                                                   short* __restrict__ projF) {
  __shared__ float xs[64][36];
  __shared__ float ps[64][36];
  const int tid = threadIdx.x;
  const int tx = tid & 15, ty = tid >> 4;
  const int m0 = blockIdx.y * 64, n0 = blockIdx.x * 64;
  float acc[4][4];
#pragma unroll
  for (int i = 0; i < 4; i++)
#pragma unroll
    for (int j = 0; j < 4; j++) acc[i][j] = 0.f;

  for (int k0 = 0; k0 < 256; k0 += 32) {
    const int r = tid >> 2, c = (tid & 3) * 8;
    *(float4*)&xs[r][c]     = *(const float4*)&x[(m0 + r) * 256 + k0 + c];
    *(float4*)&xs[r][c + 4] = *(const float4*)&x[(m0 + r) * 256 + k0 + c + 4];
    *(float4*)&ps[r][c]     = *(const float4*)&pm[(n0 + r) * 256 + k0 + c];
    *(float4*)&ps[r][c + 4] = *(const float4*)&pm[(n0 + r) * 256 + k0 + c + 4];
    __syncthreads();
#pragma unroll
    for (int kk = 0; kk < 32; kk += 4) {
      float4 xa[4], pb[4];
#pragma unroll
      for (int i = 0; i < 4; i++) xa[i] = *(const float4*)&xs[ty * 4 + i][kk];
#pragma unroll
      for (int j = 0; j < 4; j++) pb[j] = *(const float4*)&ps[tx * 4 + j][kk];
#pragma unroll
      for (int i = 0; i < 4; i++)
#pragma unroll
        for (int j = 0; j < 4; j++)
          acc[i][j] += xa[i].x * pb[j].x + xa[i].y * pb[j].y +
                       xa[i].z * pb[j].z + xa[i].w * pb[j].w;
    }
    __syncthreads();
  }
#pragma unroll
  for (int i = 0; i < 4; i++)
#pragma unroll
    for (int j = 0; j < 4; j++) {
      int b = m0 + ty * 4 + i, c = n0 + tx * 4 + j;
      int m = b * 4 + (c >> 8), k = c & 255;
      size_t addr = ((((size_t)(m >> 6) * 8 + (k >> 5)) * 4 + ((m >> 4) & 3)) * 64 +
                     ((k >> 3) & 3) * 16 + (m & 15)) * 8 + (k & 7);
      projF[addr] = f2bf(tanhf(acc[i][j]));
    }
}

// ---------------- kernel 2: pi = softmax(x @ mix_mat^T)  [1024 x 4] --------------
__global__ __launch_bounds__(256) void pi_kernel(const float* __restrict__ x,
                                                 const float* __restrict__ mm,
                                                 float* __restrict__ pi) {
  int b = blockIdx.x * 256 + threadIdx.x;
  if (b >= 1024) return;
  float acc[4] = {0.f, 0.f, 0.f, 0.f};
  for (int k = 0; k < 256; k += 4) {
    float4 xv = *(const float4*)&x[(size_t)b * 256 + k];
#pragma unroll
    for (int h = 0; h < 4; h++) {
      float4 mv = *(const float4*)&mm[h * 256 + k];
      acc[h] += xv.x * mv.x + xv.y * mv.y + xv.z * mv.z + xv.w * mv.w;
    }
  }
  float mx = fmaxf(fmaxf(acc[0], acc[1]), fmaxf(acc[2], acc[3]));
  float e[4], ssum = 0.f;
#pragma unroll
  for (int h = 0; h < 4; h++) { e[h] = __expf(acc[h] - mx); ssum += e[h]; }
#pragma unroll
  for (int h = 0; h < 4; h++) pi[b * 4 + h] = e[h] / ssum;
}

// ------- kernel 3: embB = bf16(emb * log2e), zero-padded to VPAD rows -----------
__global__ __launch_bounds__(256) void embB_kernel(const float* __restrict__ emb,
                                                   short* __restrict__ embB) {
  size_t i = ((size_t)blockIdx.x * 256 + threadIdx.x) * 8;  // element index
  size_t row = i >> 8;
  const float C = 1.44269504088896f;  // log2(e): exp(l) == exp2(l*C)
  short8 b8;
  if (row < VOCAB) {
    float4 f0 = *(const float4*)&emb[i];
    float4 f1 = *(const float4*)&emb[i + 4];
    b8[0] = f2bf(f0.x * C); b8[1] = f2bf(f0.y * C); b8[2] = f2bf(f0.z * C); b8[3] = f2bf(f0.w * C);
    b8[4] = f2bf(f1.x * C); b8[5] = f2bf(f1.y * C); b8[6] = f2bf(f1.z * C); b8[7] = f2bf(f1.w * C);
  } else {
#pragma unroll
    for (int j = 0; j < 8; ++j) b8[j] = 0;
  }
  *(short8*)&embB[i] = b8;
}

// ---------------- big GEMM: zero-LDS, zero-barrier, register-resident B ---------
// Block = one 64-col v-tile, 4 independent waves = 4 m-quarters (1024 rows each).
// Per wave: Bf[ni=4][kt=8] regs (once), loop 16 m-tiles of 64: per kt 4 coalesced
// A-frag loads (ping-pong) + 16 MFMA; epilogue per m-tile.

#define MFMA16(AF, KT)                                                                    \
  __builtin_amdgcn_s_setprio(1);                                                          \
  _Pragma("unroll") for (int mi = 0; mi < 4; ++mi)                                        \
      _Pragma("unroll") for (int ni = 0; ni < 4; ++ni)                                    \
          acc[mi][ni] = __builtin_amdgcn_mfma_f32_16x16x32_bf16(AF[mi], Bf[ni][KT],       \
                                                                acc[mi][ni], 0, 0, 0);    \
  __builtin_amdgcn_s_setprio(0);

template <int MODE>
__global__ __launch_bounds__(256, 2) void mos_gemm(const short* __restrict__ projF,
                                                   const short* __restrict__ embB_s,
                                                   const float* __restrict__ w,
                                                   float* __restrict__ part,
                                                   float* __restrict__ out) {
  const int tid = threadIdx.x;
  const int lane = tid & 63, wid = tid >> 6;
  const int l15 = lane & 15, l4 = lane >> 4;

  // bijective chunked XCD map over 1564 blocks (8 XCDs: 4x196 + 4x195)
  const int bid = blockIdx.x;
  const int xcd = bid & 7, idx = bid >> 3;
  const int vt = (xcd < 4) ? (xcd * 196 + idx) : (784 + (xcd - 4) * 195 + idx);
  const int v0 = vt * 64;
  const int M0 = wid * 1024;  // wave's m-quarter

  // ---- B fragments for full K=256, register-resident (128 VGPR) ----
  short8 Bf[4][8];
  {
    const short* bbase = embB_s + (size_t)(v0 + l15) * 256 + l4 * 8;
#pragma unroll
    for (int ni = 0; ni < 4; ++ni)
#pragma unroll
      for (int kt = 0; kt < 8; ++kt)
        Bf[ni][kt] = *(const short8*)(bbase + ni * 4096 + kt * 32);
  }

  f32x4 acc[4][4];
#pragma unroll
  for (int i = 0; i < 4; ++i)
#pragma unroll
    for (int j = 0; j < 4; ++j) acc[i][j] = (f32x4){0.f, 0.f, 0.f, 0.f};

  // A job pointer: frags (mt,kt,mi) contiguous; chunk = ((MT*8+kt)*4+mi), 512 shorts each
  const short* ap = projF + (size_t)(M0 >> 6) * 32 * 512 + lane * 8;

  short8 aA[4], aB[4];
#pragma unroll
  for (int mi = 0; mi < 4; ++mi) aA[mi] = *(const short8*)(ap + mi * 512);  // (mt0,kt0)

#pragma unroll 1
  for (int mt = 0; mt < 16; ++mt) {
#pragma unroll
    for (int kt = 0; kt < 8; kt += 2) {
      // load kt+1 into aB, compute kt with aA
#pragma unroll
      for (int mi = 0; mi < 4; ++mi)
        aB[mi] = *(const short8*)(ap + (kt + 1) * 2048 + mi * 512);
      MFMA16(aA, kt);
      // load kt+2 (kt=6 -> next m-tile's kt0; harmless overrun on last job tail)
#pragma unroll
      for (int mi = 0; mi < 4; ++mi)
        aA[mi] = *(const short8*)(ap + (kt + 2) * 2048 + mi * 512);
      MFMA16(aB, kt + 1);
    }

    // ---- epilogue for m-tile mt ----
    if (MODE == 0) {
#pragma unroll
      for (int mi = 0; mi < 4; ++mi) {
        float p[4] = {0.f, 0.f, 0.f, 0.f};
#pragma unroll
        for (int ni = 0; ni < 4; ++ni) {
          int v = v0 + ni * 16 + l15;
          bool ok = v < VOCAB;
#pragma unroll
          for (int r = 0; r < 4; ++r) {
            float e = exp2f(acc[mi][ni][r]);
            p[r] += ok ? e : 0.f;
          }
          acc[mi][ni] = (f32x4){0.f, 0.f, 0.f, 0.f};
        }
#pragma unroll
        for (int r = 0; r < 4; ++r) {
          p[r] += __shfl_xor(p[r], 1, 64);
          p[r] += __shfl_xor(p[r], 2, 64);
          p[r] += __shfl_xor(p[r], 4, 64);
          p[r] += __shfl_xor(p[r], 8, 64);
        }
        if (l15 == 0) {
          int m = M0 + mt * 64 + mi * 16 + l4 * 4;
          float4 pv = {p[0], p[1], p[2], p[3]};
          *(float4*)(part + (size_t)vt * 4096 + m) = pv;
        }
      }
    } else {
#pragma unroll
      for (int mi = 0; mi < 4; ++mi) {
        int mrow = M0 + mt * 64 + mi * 16 + l4 * 4;
        float4 wv = *(const float4*)&w[mrow];
        size_t brow = (size_t)(mrow >> 2);
#pragma unroll
        for (int ni = 0; ni < 4; ++ni) {
          int v = v0 + ni * 16 + l15;
          float val = wv.x * exp2f(acc[mi][ni][0]) + wv.y * exp2f(acc[mi][ni][1]) +
                      wv.z * exp2f(acc[mi][ni][2]) + wv.w * exp2f(acc[mi][ni][3]);
          if (v < VOCAB) out[brow * VOCAB + v] = val;
          acc[mi][ni] = (f32x4){0.f, 0.f, 0.f, 0.f};
        }
      }
    }
    ap += 16384;  // next m-tile (32 chunks * 512 shorts)
  }
}

// ---------------- reduce partials + w = pi / s ----------------------------------
__global__ __launch_bounds__(256) void reduce_w(const float* __restrict__ part,
                                                const float* __restrict__ pi,
                                                float* __restrict__ w) {
  int m = blockIdx.x * 256 + threadIdx.x;  // 0..4095
  float sum = 0.f;
  for (int c = 0; c < NVT; ++c) sum += part[(size_t)c * 4096 + m];
  w[m] = pi[m] / sum;
}

extern "C" void kernel_launch(void* const* d_in, const int* in_sizes, int n_in,
                              void* d_out, int out_size, void* d_ws, size_t ws_size,
                              hipStream_t stream) {
  const float* x        = (const float*)d_in[0];
  const float* proj_mat = (const float*)d_in[1];
  const float* mix_mat  = (const float*)d_in[2];
  const float* emb      = (const float*)d_in[3];
  float* out = (float*)d_out;

  char* ws = (char*)d_ws;
  short* projF = (short*)ws;                           // bf16 frag-order, 2 MB
  float* pi    = (float*)(ws + (2u << 20));            // [4096]
  float* w     = (float*)(ws + (2u << 20) + 16384);    // [4096]
  short* embB  = (short*)(ws + (4u << 20));            // bf16 [100096][256] = 48.9 MB
  float* part  = (float*)(ws + (4u << 20) + (size_t)VPAD * 512);  // [1564][4096] = 25.6 MB

  dim3 g1(16, 16);
  proj_kernel<<<g1, 256, 0, stream>>>(x, proj_mat, projF);
  pi_kernel<<<4, 256, 0, stream>>>(x, mix_mat, pi);
  embB_kernel<<<VPAD / 8, 256, 0, stream>>>(emb, embB);

  mos_gemm<0><<<NVT, 256, 0, stream>>>(projF, embB, nullptr, part, nullptr);
  reduce_w<<<16, 256, 0, stream>>>(part, pi, w);
  mos_gemm<1><<<NVT, 256, 0, stream>>>(projF, embB, w, nullptr, out);
}

// Round 10
// 705.535 us; speedup vs baseline: 1.0508x; 1.0463x over previous
//
#include <hip/hip_runtime.h>
#include <stdint.h>

// MixtureOfSoftmaxes: B=1024, H=4, D=256, V=100000
// out[b,v] = sum_h pi[b,h] * softmax_v(proj[b,h,:]·emb[v,:])
// No-max softmax (|logits| < ~3), base-2 (embB pre-scaled by log2e):
//   pass C: part[vt][m] = sum_{v in vt} exp2(l'); reduce -> w = pi/s
//   pass D: out[b,v] = sum_h w[m]*exp2(l')
// R10 = R9 (zero-LDS zero-barrier GEMM, projF in fragment order, Bf register-
// resident) + per-wave m-tile STAGGER: each wave starts its circular m-tile loop
// at a different phase so epilogue (exp2/VALU) and load-stall windows of the 8
// waves/CU interleave instead of converging (MFMA pipe never collectively idle).

#define VOCAB 100000
#define NVT 1564   // v-tiles of 64 (covers 100096)
#define VPAD 100096

typedef __attribute__((ext_vector_type(8))) short short8;
typedef __attribute__((ext_vector_type(4))) float f32x4;

__device__ __forceinline__ short f2bf(float f) {
  uint32_t u = __float_as_uint(f);
  u = (u + 0x7FFFu + ((u >> 16) & 1u)) >> 16;
  return (short)u;
}

// ---------------- kernel 1: proj = tanh(x @ proj_mat^T) -> projF (frag order) ---
// frag layout: elem addr = ((((m>>6)*8 + (k>>5))*4 + ((m>>4)&3))*64
//                           + ((k>>3)&3)*16 + (m&15))*8 + (k&7)
// where m = b*4 + (c>>8)  (flat row of [4096][256] view), k = c&255.
__global__ __launch_bounds__(256) void proj_kernel(const float* __restrict__ x,
                                                   const float* __restrict__ pm,
                                                   short* __restrict__ projF) {
  __shared__ float xs[64][36];
  __shared__ float ps[64][36];
  const int tid = threadIdx.x;
  const int tx = tid & 15, ty = tid >> 4;
  const int m0 = blockIdx.y * 64, n0 = blockIdx.x * 64;
  float acc[4][4];
#pragma unroll
  for (int i = 0; i < 4; i++)
#pragma unroll
    for (int j = 0; j < 4; j++) acc[i][j] = 0.f;

  for (int k0 = 0; k0 < 256; k0 += 32) {
    const int r = tid >> 2, c = (tid & 3) * 8;
    *(float4*)&xs[r][c]     = *(const float4*)&x[(m0 + r) * 256 + k0 + c];
    *(float4*)&xs[r][c + 4] = *(const float4*)&x[(m0 + r) * 256 + k0 + c + 4];
    *(float4*)&ps[r][c]     = *(const float4*)&pm[(n0 + r) * 256 + k0 + c];
    *(float4*)&ps[r][c + 4] = *(const float4*)&pm[(n0 + r) * 256 + k0 + c + 4];
    __syncthreads();
#pragma unroll
    for (int kk = 0; kk < 32; kk += 4) {
      float4 xa[4], pb[4];
#pragma unroll
      for (int i = 0; i < 4; i++) xa[i] = *(const float4*)&xs[ty * 4 + i][kk];
#pragma unroll
      for (int j = 0; j < 4; j++) pb[j] = *(const float4*)&ps[tx * 4 + j][kk];
#pragma unroll
      for (int i = 0; i < 4; i++)
#pragma unroll
        for (int j = 0; j < 4; j++)
          acc[i][j] += xa[i].x * pb[j].x + xa[i].y * pb[j].y +
                       xa[i].z * pb[j].z + xa[i].w * pb[j].w;
    }
    __syncthreads();
  }
#pragma unroll
  for (int i = 0; i < 4; i++)
#pragma unroll
    for (int j = 0; j < 4; j++) {
      int b = m0 + ty * 4 + i, c = n0 + tx * 4 + j;
      int m = b * 4 + (c >> 8), k = c & 255;
      size_t addr = ((((size_t)(m >> 6) * 8 + (k >> 5)) * 4 + ((m >> 4) & 3)) * 64 +
                     ((k >> 3) & 3) * 16 + (m & 15)) * 8 + (k & 7);
      projF[addr] = f2bf(tanhf(acc[i][j]));
    }
}

// ---------------- kernel 2: pi = softmax(x @ mix_mat^T)  [1024 x 4] --------------
__global__ __launch_bounds__(256) void pi_kernel(const float* __restrict__ x,
                                                 const float* __restrict__ mm,
                                                 float* __restrict__ pi) {
  int b = blockIdx.x * 256 + threadIdx.x;
  if (b >= 1024) return;
  float acc[4] = {0.f, 0.f, 0.f, 0.f};
  for (int k = 0; k < 256; k += 4) {
    float4 xv = *(const float4*)&x[(size_t)b * 256 + k];
#pragma unroll
    for (int h = 0; h < 4; h++) {
      float4 mv = *(const float4*)&mm[h * 256 + k];
      acc[h] += xv.x * mv.x + xv.y * mv.y + xv.z * mv.z + xv.w * mv.w;
    }
  }
  float mx = fmaxf(fmaxf(acc[0], acc[1]), fmaxf(acc[2], acc[3]));
  float e[4], ssum = 0.f;
#pragma unroll
  for (int h = 0; h < 4; h++) { e[h] = __expf(acc[h] - mx); ssum += e[h]; }
#pragma unroll
  for (int h = 0; h < 4; h++) pi[b * 4 + h] = e[h] / ssum;
}

// ------- kernel 3: embB = bf16(emb * log2e), zero-padded to VPAD rows -----------
__global__ __launch_bounds__(256) void embB_kernel(const float* __restrict__ emb,
                                                   short* __restrict__ embB) {
  size_t i = ((size_t)blockIdx.x * 256 + threadIdx.x) * 8;  // element index
  size_t row = i >> 8;
  const float C = 1.44269504088896f;  // log2(e): exp(l) == exp2(l*C)
  short8 b8;
  if (row < VOCAB) {
    float4 f0 = *(const float4*)&emb[i];
    float4 f1 = *(const float4*)&emb[i + 4];
    b8[0] = f2bf(f0.x * C); b8[1] = f2bf(f0.y * C); b8[2] = f2bf(f0.z * C); b8[3] = f2bf(f0.w * C);
    b8[4] = f2bf(f1.x * C); b8[5] = f2bf(f1.y * C); b8[6] = f2bf(f1.z * C); b8[7] = f2bf(f1.w * C);
  } else {
#pragma unroll
    for (int j = 0; j < 8; ++j) b8[j] = 0;
  }
  *(short8*)&embB[i] = b8;
}

// ---------------- big GEMM: zero-LDS, zero-barrier, staggered waves -------------
// Block = one 64-col v-tile, 4 independent waves = 4 m-quarters (1024 rows each).
// Per wave: Bf[ni=4][kt=8] regs (once), circular loop over 16 m-tiles of 64
// starting at a per-wave phase; per kt: 4 coalesced A-frag loads (ping-pong) +
// 16 MFMA; epilogue per m-tile (now phase-staggered across the CU's 8 waves).

#define MFMA16(AF, KT)                                                                    \
  __builtin_amdgcn_s_setprio(1);                                                          \
  _Pragma("unroll") for (int mi = 0; mi < 4; ++mi)                                        \
      _Pragma("unroll") for (int ni = 0; ni < 4; ++ni)                                    \
          acc[mi][ni] = __builtin_amdgcn_mfma_f32_16x16x32_bf16(AF[mi], Bf[ni][KT],       \
                                                                acc[mi][ni], 0, 0, 0);    \
  __builtin_amdgcn_s_setprio(0);

template <int MODE>
__global__ __launch_bounds__(256, 2) void mos_gemm(const short* __restrict__ projF,
                                                   const short* __restrict__ embB_s,
                                                   const float* __restrict__ w,
                                                   float* __restrict__ part,
                                                   float* __restrict__ out) {
  const int tid = threadIdx.x;
  const int lane = tid & 63, wid = tid >> 6;
  const int l15 = lane & 15, l4 = lane >> 4;

  // bijective chunked XCD map over 1564 blocks (8 XCDs: 4x196 + 4x195)
  const int bid = blockIdx.x;
  const int xcd = bid & 7, idx = bid >> 3;
  const int vt = (xcd < 4) ? (xcd * 196 + idx) : (784 + (xcd - 4) * 195 + idx);
  const int v0 = vt * 64;
  const int M0 = wid * 1024;  // wave's m-quarter

  // per-wave m-tile start phase: spreads the 8 waves/CU across 16 phases
  const int mts = (wid * 4 + idx) & 15;

  // ---- B fragments for full K=256, register-resident (128 VGPR) ----
  short8 Bf[4][8];
  {
    const short* bbase = embB_s + (size_t)(v0 + l15) * 256 + l4 * 8;
#pragma unroll
    for (int ni = 0; ni < 4; ++ni)
#pragma unroll
      for (int kt = 0; kt < 8; ++kt)
        Bf[ni][kt] = *(const short8*)(bbase + ni * 4096 + kt * 32);
  }

  f32x4 acc[4][4];
#pragma unroll
  for (int i = 0; i < 4; ++i)
#pragma unroll
    for (int j = 0; j < 4; ++j) acc[i][j] = (f32x4){0.f, 0.f, 0.f, 0.f};

  // A quarter base: frags (mt,kt,mi) contiguous; chunk = ((mt*8+kt)*4+mi), 512 shorts
  const short* aq = projF + (size_t)(M0 >> 6) * 32 * 512 + lane * 8;

  const short* ap = aq + mts * 16384;
  short8 aA[4], aB[4];
#pragma unroll
  for (int mi = 0; mi < 4; ++mi) aA[mi] = *(const short8*)(ap + mi * 512);  // (mts,kt0)

#pragma unroll 1
  for (int it = 0; it < 16; ++it) {
    const int mt = (mts + it) & 15;
    ap = aq + mt * 16384;
#pragma unroll
    for (int kt = 0; kt < 8; kt += 2) {
      // load kt+1 into aB, compute kt with aA
#pragma unroll
      for (int mi = 0; mi < 4; ++mi)
        aB[mi] = *(const short8*)(ap + (kt + 1) * 2048 + mi * 512);
      MFMA16(aA, kt);
      // load kt+2 (kt=6 -> mt+1 linear neighbor's kt0; dangling-but-mapped at ends)
#pragma unroll
      for (int mi = 0; mi < 4; ++mi)
        aA[mi] = *(const short8*)(ap + (kt + 2) * 2048 + mi * 512);
      MFMA16(aB, kt + 1);
    }
    // fix ping for next iteration when the circular walk wraps (mt=15 -> 0)
    if (mt == 15 && it < 15) {
#pragma unroll
      for (int mi = 0; mi < 4; ++mi) aA[mi] = *(const short8*)(aq + mi * 512);
    }

    // ---- epilogue for m-tile mt ----
    if (MODE == 0) {
#pragma unroll
      for (int mi = 0; mi < 4; ++mi) {
        float p[4] = {0.f, 0.f, 0.f, 0.f};
#pragma unroll
        for (int ni = 0; ni < 4; ++ni) {
          int v = v0 + ni * 16 + l15;
          bool ok = v < VOCAB;
#pragma unroll
          for (int r = 0; r < 4; ++r) {
            float e = exp2f(acc[mi][ni][r]);
            p[r] += ok ? e : 0.f;
          }
          acc[mi][ni] = (f32x4){0.f, 0.f, 0.f, 0.f};
        }
#pragma unroll
        for (int r = 0; r < 4; ++r) {
          p[r] += __shfl_xor(p[r], 1, 64);
          p[r] += __shfl_xor(p[r], 2, 64);
          p[r] += __shfl_xor(p[r], 4, 64);
          p[r] += __shfl_xor(p[r], 8, 64);
        }
        if (l15 == 0) {
          int m = M0 + mt * 64 + mi * 16 + l4 * 4;
          float4 pv = {p[0], p[1], p[2], p[3]};
          *(float4*)(part + (size_t)vt * 4096 + m) = pv;
        }
      }
    } else {
#pragma unroll
      for (int mi = 0; mi < 4; ++mi) {
        int mrow = M0 + mt * 64 + mi * 16 + l4 * 4;
        float4 wv = *(const float4*)&w[mrow];
        size_t brow = (size_t)(mrow >> 2);
#pragma unroll
        for (int ni = 0; ni < 4; ++ni) {
          int v = v0 + ni * 16 + l15;
          float val = wv.x * exp2f(acc[mi][ni][0]) + wv.y * exp2f(acc[mi][ni][1]) +
                      wv.z * exp2f(acc[mi][ni][2]) + wv.w * exp2f(acc[mi][ni][3]);
          if (v < VOCAB) out[brow * VOCAB + v] = val;
          acc[mi][ni] = (f32x4){0.f, 0.f, 0.f, 0.f};
        }
      }
    }
  }
}

// ---------------- reduce partials + w = pi / s ----------------------------------
__global__ __launch_bounds__(256) void reduce_w(const float* __restrict__ part,
                                                const float* __restrict__ pi,
                                                float* __restrict__ w) {
  int m = blockIdx.x * 256 + threadIdx.x;  // 0..4095
  float sum = 0.f;
  for (int c = 0; c < NVT; ++c) sum += part[(size_t)c * 4096 + m];
  w[m] = pi[m] / sum;
}

extern "C" void kernel_launch(void* const* d_in, const int* in_sizes, int n_in,
                              void* d_out, int out_size, void* d_ws, size_t ws_size,
                              hipStream_t stream) {
  const float* x        = (const float*)d_in[0];
  const float* proj_mat = (const float*)d_in[1];
  const float* mix_mat  = (const float*)d_in[2];
  const float* emb      = (const float*)d_in[3];
  float* out = (float*)d_out;

  char* ws = (char*)d_ws;
  short* projF = (short*)ws;                           // bf16 frag-order, 2 MB
  float* pi    = (float*)(ws + (2u << 20));            // [4096]
  float* w     = (float*)(ws + (2u << 20) + 16384);    // [4096]
  short* embB  = (short*)(ws + (4u << 20));            // bf16 [100096][256] = 48.9 MB
  float* part  = (float*)(ws + (4u << 20) + (size_t)VPAD * 512);  // [1564][4096] = 25.6 MB

  dim3 g1(16, 16);
  proj_kernel<<<g1, 256, 0, stream>>>(x, proj_mat, projF);
  pi_kernel<<<4, 256, 0, stream>>>(x, mix_mat, pi);
  embB_kernel<<<VPAD / 8, 256, 0, stream>>>(emb, embB);

  mos_gemm<0><<<NVT, 256, 0, stream>>>(projF, embB, nullptr, part, nullptr);
  reduce_w<<<16, 256, 0, stream>>>(part, pi, w);
  mos_gemm<1><<<NVT, 256, 0, stream>>>(projF, embB, w, nullptr, out);
}